// Round 1
// baseline (424.421 us; speedup 1.0000x reference)
//
#include <hip/hip_runtime.h>

// EMA recurrence h_t = (1-a)*y_t + a*h_{t-1}, a=0.9, over (B=4, S=4096, D=2048) fp32.
// Chunked-scan with redundant warm-up window: chunk of length L starts its
// recurrence W steps early from h=0; truncation error = 0.9^W * |h| ~ 2e-6 for
// W=128 (threshold is 2.6e-2). Traffic: 128*(1+W/L) MiB read + 128 MiB write
// = 288 MiB -> ~46 us at 6.3 TB/s.

constexpr int B = 4;
constexpr int S = 4096;
constexpr int D = 2048;
constexpr int L = 512;   // chunk length (S/L = 8 chunks)
constexpr int W = 128;   // warm-up window; 0.9^128 ~ 1.4e-6

__global__ __launch_bounds__(256) void ema_kernel(const float* __restrict__ y,
                                                  float* __restrict__ out) {
    const int d = blockIdx.x * blockDim.x + threadIdx.x;   // 0..D-1
    const int c = blockIdx.y;                               // chunk index
    const int b = blockIdx.z;

    const long long base = (long long)b * S * D + d;
    const int sm = c * L;            // first stored element
    int s0 = sm - W;                 // warm-up start
    if (s0 < 0) s0 = 0;              // chunk 0: exact start, h_{-1}=0

    float h = 0.0f;
    const float* __restrict__ p = y + base + (long long)s0 * D;

    // warm-up: no stores (trip count 0 or W, wave-uniform)
    #pragma unroll 8
    for (int s = s0; s < sm; ++s) {
        h = fmaf(0.9f, h, 0.1f * (*p));   // dep chain = 1 fma/step
        p += D;
    }

    // main: compute + store L elements
    float* __restrict__ q = out + base + (long long)sm * D;
    #pragma unroll 8
    for (int s = 0; s < L; ++s) {
        h = fmaf(0.9f, h, 0.1f * (*p));
        *q = h;
        p += D;
        q += D;
    }
}

extern "C" void kernel_launch(void* const* d_in, const int* in_sizes, int n_in,
                              void* d_out, int out_size, void* d_ws, size_t ws_size,
                              hipStream_t stream) {
    const float* y = (const float*)d_in[0];
    float* out = (float*)d_out;

    dim3 block(256, 1, 1);
    dim3 grid(D / 256, S / L, B);   // (8, 8, 4) = 256 blocks
    ema_kernel<<<grid, block, 0, stream>>>(y, out);
}

// Round 3
// 238.462 us; speedup vs baseline: 1.7798x; 1.7798x over previous
//
#include <hip/hip_runtime.h>

// EMA h_t = 0.1*y_t + 0.9*h_{t-1} over (B=4, S=4096, D=2048) fp32.
// Chunked scan with redundant warm-up (W=64 -> truncation err ~1.5e-3,
// threshold 2.6e-2). R1 post-mortem: one HBM latency per iteration
// (latency-bound). Fix: explicit register batching (T=16 independent
// 16B loads in flight), vec4 per thread, shorter chunks, nontemporal
// stores. R2 compile fix: native ext_vector_type instead of HIP float4
// (nontemporal builtin requires real vector type).

typedef float v4 __attribute__((ext_vector_type(4)));

constexpr int B  = 4;
constexpr int S  = 4096;
constexpr int D  = 2048;
constexpr int D4 = D / 4;     // 512 vec4 lanes per row
constexpr int L  = 128;       // chunk length  (S/L = 32 chunks)
constexpr int W  = 64;        // warm-up window (0.9^64 ~ 1.2e-3)
constexpr int T  = 16;        // loads kept in flight per thread

__global__ __launch_bounds__(256) void ema_kernel(const v4* __restrict__ y,
                                                  v4* __restrict__ out) {
    const int d4 = blockIdx.x * blockDim.x + threadIdx.x;   // 0..D4-1
    const int c  = blockIdx.y;                              // chunk
    const int b  = blockIdx.z;

    const long long base = (long long)b * S * D4 + d4;
    const int sm = c * L;                                   // first stored step

    v4 h = (v4)(0.0f);
    const v4* __restrict__ p;

    if (c != 0) {
        // warm-up: W steps, no stores, batched T at a time
        p = y + base + (long long)(sm - W) * D4;
        for (int g = 0; g < W / T; ++g) {
            v4 buf[T];
            #pragma unroll
            for (int t = 0; t < T; ++t) buf[t] = p[t * D4];   // independent
            #pragma unroll
            for (int t = 0; t < T; ++t)
                h = 0.9f * h + 0.1f * buf[t];
            p += T * D4;
        }
    } else {
        p = y + base;   // chunk 0: exact start from h_{-1}=0
    }

    // main: L steps, compute + streaming store
    v4* __restrict__ q = out + base + (long long)sm * D4;
    for (int g = 0; g < L / T; ++g) {
        v4 buf[T];
        #pragma unroll
        for (int t = 0; t < T; ++t) buf[t] = p[t * D4];       // independent
        #pragma unroll
        for (int t = 0; t < T; ++t) {
            h = 0.9f * h + 0.1f * buf[t];
            __builtin_nontemporal_store(h, q + t * D4);       // write-once output
        }
        p += T * D4;
        q += T * D4;
    }
}

extern "C" void kernel_launch(void* const* d_in, const int* in_sizes, int n_in,
                              void* d_out, int out_size, void* d_ws, size_t ws_size,
                              hipStream_t stream) {
    const v4* y = (const v4*)d_in[0];
    v4* out = (v4*)d_out;

    dim3 block(256, 1, 1);
    dim3 grid(D4 / 256, S / L, B);   // (2, 32, 4) = 256 blocks, 1/CU
    ema_kernel<<<grid, block, 0, stream>>>(y, out);
}

// Round 4
// 236.503 us; speedup vs baseline: 1.7946x; 1.0083x over previous
//
#include <hip/hip_runtime.h>

// EMA h_t = 0.1*y_t + 0.9*h_{t-1} over (B=4, S=4096, D=2048) fp32.
// Chunked scan, redundant warm-up W=64 (truncation ~1.5e-3, threshold 2.6e-2).
// R3 post-mortem: VGPR=36 proves the compiler re-rolled the buf[16] batch ->
// one HBM latency per step (450 ns/step). R4: named registers b0..b7 in a
// rolling pipeline (consume b_i, immediately re-issue b_i) -> steady 8
// independent 16B loads in flight per thread, s_waitcnt vmcnt(7) not vmcnt(0).

typedef float v4 __attribute__((ext_vector_type(4)));

constexpr int B  = 4;
constexpr int S  = 4096;
constexpr int D  = 2048;
constexpr int D4 = D / 4;     // 512 vec4 lanes per row
constexpr int L  = 128;       // chunk length  (S/L = 32 chunks)
constexpr int W  = 64;        // warm-up window (0.9^64 ~ 1.2e-3)

__global__ __launch_bounds__(256, 1) void ema_kernel(const v4* __restrict__ y,
                                                     v4* __restrict__ out) {
    const int d4 = blockIdx.x * blockDim.x + threadIdx.x;   // 0..D4-1
    const int c  = blockIdx.y;                              // chunk
    const int b  = blockIdx.z;

    const long long base = (long long)b * S * D4 + d4;
    const int sm = c * L;                                   // first stored step

    v4 h = (v4)(0.0f);
    const v4* __restrict__ p;

    v4 b0, b1, b2, b3, b4, b5, b6, b7;

#define LOAD_ALL() do {            \
        b0 = p[0 * D4];            \
        b1 = p[1 * D4];            \
        b2 = p[2 * D4];            \
        b3 = p[3 * D4];            \
        b4 = p[4 * D4];            \
        b5 = p[5 * D4];            \
        b6 = p[6 * D4];            \
        b7 = p[7 * D4];            \
        p += 8 * D4;               \
    } while (0)

#define EMA(bi) h = 0.9f * h + 0.1f * (bi)

    if (c != 0) {
        // ---- warm-up: W steps, no stores, rolling 8-deep pipeline ----
        p = y + base + (long long)(sm - W) * D4;
        LOAD_ALL();
        #pragma unroll 1
        for (int g = 0; g < W / 8 - 1; ++g) {
            EMA(b0); b0 = p[0 * D4];
            EMA(b1); b1 = p[1 * D4];
            EMA(b2); b2 = p[2 * D4];
            EMA(b3); b3 = p[3 * D4];
            EMA(b4); b4 = p[4 * D4];
            EMA(b5); b5 = p[5 * D4];
            EMA(b6); b6 = p[6 * D4];
            EMA(b7); b7 = p[7 * D4];
            p += 8 * D4;
        }
        EMA(b0); EMA(b1); EMA(b2); EMA(b3);
        EMA(b4); EMA(b5); EMA(b6); EMA(b7);
    } else {
        p = y + base;   // chunk 0: exact start from h_{-1}=0
    }

    // ---- main: L steps, compute + nontemporal store, rolling pipeline ----
    v4* __restrict__ q = out + base + (long long)sm * D4;
    LOAD_ALL();

#define STEP(i, bi)                                         \
        EMA(bi);                                            \
        __builtin_nontemporal_store(h, q + (i) * D4);       \
        bi = p[(i) * D4]

    #pragma unroll 1
    for (int g = 0; g < L / 8 - 1; ++g) {
        STEP(0, b0);
        STEP(1, b1);
        STEP(2, b2);
        STEP(3, b3);
        STEP(4, b4);
        STEP(5, b5);
        STEP(6, b6);
        STEP(7, b7);
        p += 8 * D4;
        q += 8 * D4;
    }
    // epilogue: consume final batch
    EMA(b0); __builtin_nontemporal_store(h, q + 0 * D4);
    EMA(b1); __builtin_nontemporal_store(h, q + 1 * D4);
    EMA(b2); __builtin_nontemporal_store(h, q + 2 * D4);
    EMA(b3); __builtin_nontemporal_store(h, q + 3 * D4);
    EMA(b4); __builtin_nontemporal_store(h, q + 4 * D4);
    EMA(b5); __builtin_nontemporal_store(h, q + 5 * D4);
    EMA(b6); __builtin_nontemporal_store(h, q + 6 * D4);
    EMA(b7); __builtin_nontemporal_store(h, q + 7 * D4);

#undef STEP
#undef EMA
#undef LOAD_ALL
}

extern "C" void kernel_launch(void* const* d_in, const int* in_sizes, int n_in,
                              void* d_out, int out_size, void* d_ws, size_t ws_size,
                              hipStream_t stream) {
    const v4* y = (const v4*)d_in[0];
    v4* out = (v4*)d_out;

    dim3 block(256, 1, 1);
    dim3 grid(D4 / 256, S / L, B);   // (2, 32, 4) = 256 blocks, 1/CU
    ema_kernel<<<grid, block, 0, stream>>>(y, out);
}